// Round 4
// baseline (120.438 us; speedup 1.0000x reference)
//
#include <hip/hip_runtime.h>

// BinaryConv2dSkip1x1 forward, MI355X — full-MFMA version.
// out = RPReLU( conv3x3( sign(x+mb), sf*sign(w), pad=1 ) ) + conv1x1(x, skip_w) + skip_b
//
// Binary conv: sign bits expanded to +/-1 int8 planes in LDS (halo/out-of-bounds
// stored as 0 => exact zero padding, no correction table), computed with
// mfma_i32_16x16x64_i8 (one K=64 MFMA per tap; S exact in i32).
// Skip 1x1 conv: bf16 mfma_f32_16x16x32_bf16 over K=64 in two 32-ch passes.
// Both accumulators share the 16x16 C/D layout (col=lane&15, row=(lane>>4)*4+reg),
// combined in the epilogue and stored directly (no LDS round trip).

#define HW (256*256)

typedef __bf16 bf16x8 __attribute__((ext_vector_type(8)));
typedef float  f32x4  __attribute__((ext_vector_type(4)));
typedef int    i32x4  __attribute__((ext_vector_type(4)));

__device__ __forceinline__ void lds_fence() {
    asm volatile("s_waitcnt lgkmcnt(0)" ::: "memory");
}

// expand 4 sign bits -> 4 i8 bytes (+1 for bit=0, -1 for bit=1)
__device__ __forceinline__ int expand4(unsigned int nib) {
    unsigned int spread = (nib * 0x00204081u) & 0x01010101u;  // bit i -> byte i LSB
    return (int)(0x01010101u ^ (spread * 0xFEu));             // 0x01 or 0xFF per byte
}

// ---------------- prep kernel: one block, 576 threads (o = tid/9, t = tid%9) ----------
__global__ void bq_prep_kernel(const float* __restrict__ weight,   // [64][64][3][3]
                               const float* __restrict__ pr_bias0,
                               const float* __restrict__ prelu_w,
                               const float* __restrict__ pr_bias1,
                               const float* __restrict__ skip_b,
                               const float* __restrict__ skipw,    // [64][64]
                               char* __restrict__ afrag,           // [4rt][9t][64 lane][16] i8
                               unsigned short* __restrict__ swfrag,// [4rt][2p][64 lane][8] bf16
                               float* __restrict__ consg) {        // [64][4]
    __shared__ float sabs_l[576];
    const int tid = threadIdx.x;
    const int o = tid / 9, t = tid % 9;
    const int m = o & 15, rt = o >> 4;
    float sabs = 0.f;
    for (int ch = 0; ch < 64; ++ch) {
        float wv = weight[(o*64 + ch)*9 + t];
        sabs += fabsf(wv);
        // lane l = m + 16*(ch>>4) holds A[m][k], k=(l>>4)*16 + (ch&15)
        afrag[((rt*9 + t)*64 + (m + 16*(ch >> 4)))*16 + (ch & 15)] =
            (wv < 0.f) ? (char)-1 : (char)1;
    }
    sabs_l[tid] = sabs;
    __syncthreads();
    if (t == 0) {
        float s = 0.f;
        #pragma unroll
        for (int k = 0; k < 9; ++k) s += sabs_l[o*9 + k];
        float sf = s / 576.f;
        consg[o*4 + 0] = sf;
        consg[o*4 + 1] = pr_bias0[o];
        consg[o*4 + 2] = prelu_w[o];
        consg[o*4 + 3] = pr_bias1[o] + skip_b[o];
    }
    if (t == 1) {
        for (int p = 0; p < 2; ++p)
            for (int gg = 0; gg < 4; ++gg)
                for (int i = 0; i < 8; ++i) {
                    float wv = skipw[o*64 + p*32 + gg*8 + i];
                    swfrag[((rt*2 + p)*64 + (m + 16*gg))*8 + i] =
                        __builtin_bit_cast(unsigned short, (__bf16)wv);
                }
    }
}

// ---------------- main kernel: tile 32 px x 8 rows, 512 threads (wave = one row) ------
__global__ __launch_bounds__(512, 4)
void bq_main_kernel(const float* __restrict__ x,        // [8][64][256][256]
                    const float* __restrict__ mb,       // [64]
                    const char* __restrict__ afrag,
                    const unsigned short* __restrict__ swfrag,
                    const float* __restrict__ consg,
                    float* __restrict__ out) {
    __shared__ __align__(16) char A_lds[4*9*64*16];            // 36864 B
    __shared__ __align__(16) char planes[10*4*34*16];          // 21760 B: [row][slot16ch][px][16]
    __shared__ __align__(16) unsigned short xslots[8*4*32*8];  // 16384 B: [wave][slot8ch][px][8bf16]
    __shared__ __align__(16) float cons[64*4];                 // 1024 B

    const int tid = threadIdx.x;
    const int l = tid & 63, w = tid >> 6;
    const int mypx = l & 31, chh = l >> 5;
    const int lg = l >> 4, lr = l & 15;
    const int bxp = blockIdx.x, byp = blockIdx.y, b = blockIdx.z;
    const int h0 = byp*8 + w, px0 = bxp*32;
    const int pix = h0*256 + px0 + mypx;
    const float* xb = x + (size_t)b * 64 * HW;

    for (int i = tid; i < 2304; i += 512)
        ((i32x4*)A_lds)[i] = ((const i32x4*)afrag)[i];
    if (tid < 64) ((f32x4*)cons)[tid] = ((const f32x4*)consg)[tid];

    f32x4 skacc[4][2];
    #pragma unroll
    for (int rt = 0; rt < 4; ++rt)
        #pragma unroll
        for (int g = 0; g < 2; ++g) skacc[rt][g] = (f32x4){0.f, 0.f, 0.f, 0.f};

    // Phase A: two 32-ch passes. Each lane covers 16 ch of its pixel.
    // Pass p, lane half chh: ch = p*32 + chh*16 + j.
    unsigned int bits[2];
    #pragma unroll
    for (int p = 0; p < 2; ++p) {
        unsigned int bb = 0;
        bf16x8 v0, v1;
        #pragma unroll
        for (int j = 0; j < 16; ++j) {
            const int ch = p*32 + chh*16 + j;
            float xv = xb[(size_t)ch*HW + pix];
            bb |= (__float_as_uint(xv + mb[ch]) >> 31) << j;
            if (j < 8) v0[j] = (__bf16)xv; else v1[j-8] = (__bf16)xv;
        }
        bits[p] = bb;
        // bf16 slots: slot = chh*2 + {0,1} holds ch (p*32 + slot*8 .. +7)
        *(bf16x8*)&xslots[((w*4 + chh*2 + 0)*32 + mypx)*8] = v0;
        *(bf16x8*)&xslots[((w*4 + chh*2 + 1)*32 + mypx)*8] = v1;
        lds_fence();   // wave-synchronous: own wave's region
        bf16x8 bx[2];
        #pragma unroll
        for (int g = 0; g < 2; ++g)
            bx[g] = *(const bf16x8*)&xslots[((w*4 + lg)*32 + g*16 + lr)*8];
        #pragma unroll
        for (int rt = 0; rt < 4; ++rt) {
            bf16x8 sa = *(const bf16x8*)&swfrag[((rt*2 + p)*64 + l)*8];
            #pragma unroll
            for (int g = 0; g < 2; ++g)
                skacc[rt][g] = __builtin_amdgcn_mfma_f32_16x16x32_bf16(
                    sa, bx[g], skacc[rt][g], 0, 0, 0);
        }
        lds_fence();   // reads done before next pass overwrites
    }

    // Interior sign planes: slot s = chh + 2*p holds ch s*16..s*16+15 of this px.
    #pragma unroll
    for (int p = 0; p < 2; ++p) {
        const int s = chh + 2*p;
        i32x4 dw;
        dw[0] = expand4(bits[p] & 15);
        dw[1] = expand4((bits[p] >> 4) & 15);
        dw[2] = expand4((bits[p] >> 8) & 15);
        dw[3] = expand4((bits[p] >> 12) & 15);
        *(i32x4*)&planes[(((w + 1)*4 + s)*34 + mypx + 1)*16] = dw;
    }

    // Halo planes: 84 px (rows -1/+8, cols -1/+32) x 2 ch-halves = 168 jobs.
    if (tid < 168) {
        const int idx = tid >> 1, hh = tid & 1;
        int r, c;
        if (idx < 34)      { r = 0;        c = idx;      }
        else if (idx < 68) { r = 9;        c = idx - 34; }
        else if (idx < 76) { r = idx - 67; c = 0;        }   // r = 1..8
        else               { r = idx - 75; c = 33;       }   // r = 1..8
        const int hg = byp*8 + r - 1, wg = px0 + c - 1;
        const bool inb = (hg >= 0 && hg < 256 && wg >= 0 && wg < 256);
        #pragma unroll
        for (int p = 0; p < 2; ++p) {
            i32x4 dw = (i32x4){0, 0, 0, 0};          // OOB => 0 bytes = exact zero-pad
            if (inb) {
                unsigned int bb = 0;
                const int po = hg*256 + wg;
                #pragma unroll
                for (int j = 0; j < 16; ++j) {
                    const int ch = p*32 + hh*16 + j;
                    bb |= (__float_as_uint(xb[(size_t)ch*HW + po] + mb[ch]) >> 31) << j;
                }
                dw[0] = expand4(bb & 15);
                dw[1] = expand4((bb >> 4) & 15);
                dw[2] = expand4((bb >> 8) & 15);
                dw[3] = expand4((bb >> 12) & 15);
            }
            *(i32x4*)&planes[((r*4 + (hh + 2*p))*34 + c)*16] = dw;
        }
    }
    __syncthreads();

    // Phase C: binary conv via i8 MFMA + fused epilogue.
    // B-frag for tap (dr,dc), px-group g: plane row w+dr, slot lg, col lr+dc+g*16.
    const int prow_base = ((w*4 + lg)*34 + lr)*16;
    float* outp = out + (size_t)b*64*HW + h0*256 + px0;

    #pragma unroll
    for (int rt = 0; rt < 4; ++rt) {
        i32x4 bacc0 = (i32x4){0,0,0,0}, bacc1 = (i32x4){0,0,0,0};
        #pragma unroll
        for (int t = 0; t < 9; ++t) {
            const int dr = t / 3, dc = t % 3;   // 0..2 (row w+dr-1+1, col offset dc-1+1)
            i32x4 a  = *(const i32x4*)&A_lds[((rt*9 + t)*64 + l)*16];
            i32x4 b0 = *(const i32x4*)&planes[prow_base + dr*(4*34*16) + dc*16];
            i32x4 b1 = *(const i32x4*)&planes[prow_base + dr*(4*34*16) + dc*16 + 256];
            bacc0 = __builtin_amdgcn_mfma_i32_16x16x64_i8(a, b0, bacc0, 0, 0, 0);
            bacc1 = __builtin_amdgcn_mfma_i32_16x16x64_i8(a, b1, bacc1, 0, 0, 0);
        }
        #pragma unroll
        for (int qi = 0; qi < 4; ++qi) {
            const int o = rt*16 + lg*4 + qi;
            f32x4 c4 = *(const f32x4*)&cons[o*4];   // (sf, pb0, aP, pb1+skip_b)
            {
                float tv = fmaf(c4[0], (float)bacc0[qi], c4[1]);
                tv = fmaxf(tv, 0.f) + c4[2]*fminf(tv, 0.f);
                outp[(size_t)o*HW + lr] = tv + c4[3] + skacc[rt][0][qi];
            }
            {
                float tv = fmaf(c4[0], (float)bacc1[qi], c4[1]);
                tv = fmaxf(tv, 0.f) + c4[2]*fminf(tv, 0.f);
                outp[(size_t)o*HW + 16 + lr] = tv + c4[3] + skacc[rt][1][qi];
            }
        }
    }
}

extern "C" void kernel_launch(void* const* d_in, const int* in_sizes, int n_in,
                              void* d_out, int out_size, void* d_ws, size_t ws_size,
                              hipStream_t stream) {
    const float* x      = (const float*)d_in[0];
    const float* mb     = (const float*)d_in[1];
    const float* weight = (const float*)d_in[2];
    const float* pb0    = (const float*)d_in[3];
    const float* pw     = (const float*)d_in[4];
    const float* pb1    = (const float*)d_in[5];
    const float* skw    = (const float*)d_in[6];
    const float* skb    = (const float*)d_in[7];
    float* out = (float*)d_out;

    char* ws = (char*)d_ws;
    char*           afrag  = ws;                               // 36864 B
    unsigned short* swfrag = (unsigned short*)(ws + 36864);    //  8192 B
    float*          consg  = (float*)(ws + 45056);             //  1024 B (total 46080)

    hipLaunchKernelGGL(bq_prep_kernel, dim3(1), dim3(576), 0, stream,
                       weight, pb0, pw, pb1, skb, skw, afrag, swfrag, consg);
    hipLaunchKernelGGL(bq_main_kernel, dim3(8, 32, 8), dim3(512), 0, stream,
                       x, mb, afrag, swfrag, consg, out);
}